// Round 15
// baseline (168.643 us; speedup 1.0000x reference)
//
#include <hip/hip_runtime.h>
#include <hip/hip_fp16.h>
#include <math.h>

#define DD 384
#define HD 1024
#define CD 256
#define NS 765        // 2*DD-1 shifts
#define NITER 4
#define NROWS 256     // B*T
#define TEMPER_F 10.0f
#define EPSF 1e-6f
#define CUTF 1e-10f

typedef unsigned long long u64;
typedef unsigned int u32;
typedef _Float16 hh2 __attribute__((ext_vector_type(2)));

// monotone float->uint (ascending)
__device__ __forceinline__ u32 flipf(float f) {
    u32 u = __float_as_uint(f);
    return u ^ ((u32)((int)u >> 31) | 0x80000000u);
}
// fp32 -> bf16 (RTNE), packed pair
__device__ __forceinline__ u32 bf16r(float f) {
    u32 u = __float_as_uint(f);
    return (u + 0x7FFFu + ((u >> 16) & 1u)) >> 16;
}
__device__ __forceinline__ u32 pack2bf(float a, float b) {
    return bf16r(a) | (bf16r(b) << 16);
}
__device__ __forceinline__ float blo(u32 p) { return __uint_as_float(p << 16); }
__device__ __forceinline__ float bhi(u32 p) { return __uint_as_float(p & 0xFFFF0000u); }
// fp32 pair -> packed f16 (RTNE)
__device__ __forceinline__ u32 packh2(float a, float b) {
    __half2 p = __floats2half2_rn(a, b);
    return __builtin_bit_cast(u32, p);
}
// fp32 += dot2(f16x2, f16x2)
__device__ __forceinline__ float dot2(u32 a, u32 b, float c) {
#if __has_builtin(__builtin_amdgcn_fdot2)
    return __builtin_amdgcn_fdot2(__builtin_bit_cast(hh2, a),
                                  __builtin_bit_cast(hh2, b), c, false);
#else
    __half2 ah = __builtin_bit_cast(__half2, a);
    __half2 bh = __builtin_bit_cast(__half2, b);
    return fmaf(__half2float(ah.y), __half2float(bh.y),
           fmaf(__half2float(ah.x), __half2float(bh.x), c));
#endif
}

// ---- 0) convert weights + zero the reduction header ----
// Wenc -> f16 K-paired [192][1024] u32; Wdec -> bf16 col-paired [1024][192] u32.
__global__ __launch_bounds__(256) void convert_kernel(
    const float* __restrict__ We, const float* __restrict__ Wd,
    u32* __restrict__ hdr, u32* __restrict__ wencp, uint2* __restrict__ wd16)
{
    if (blockIdx.x == 0 && threadIdx.x < 8) hdr[threadIdx.x] = 0;
    const int t = blockIdx.x * 256 + threadIdx.x;      // 65536 threads
    for (int i = t; i < 192 * HD; i += 65536) {
        int j2 = i >> 10, c = i & 1023;
        wencp[i] = packh2(We[(2 * j2) * HD + c], We[(2 * j2 + 1) * HD + c]);
    }
    for (int i = t; i < (HD * DD) / 4; i += 65536) {
        float4 v = ((const float4*)Wd)[i];
        wd16[i] = make_uint2(pack2bf(v.x, v.y), pack2bf(v.z, v.w));
    }
}

// One 1024-thread block per row. Last-arriving block finalizes the losses.
__global__ __launch_bounds__(1024) void fused_kernel(
    const float* __restrict__ x, const float* __restrict__ y,
    const u32* __restrict__ wencp, const float* __restrict__ benc,
    const u32* __restrict__ wdec16, const float* __restrict__ bdec,
    float* __restrict__ out_xdis, float* __restrict__ gloss,
    int* __restrict__ gcnt, int* __restrict__ ticket,
    float* __restrict__ losses)
{
    const int row  = blockIdx.x;
    const int tid  = threadIdx.x;
    const int lane = tid & 63;
    const int wid  = tid >> 6;       // 0..15

    __shared__ __align__(16) float xpad[1152];
    __shared__ __align__(16) float yr[DD];
    __shared__ float xa[DD];
    __shared__ __align__(16) float xe_s[DD];
    __shared__ u32   xep[192];                    // xe packed f16 pairs
    __shared__ __align__(16) float part[4][HD];   // encoder K-split partials
    __shared__ u32   sk0[HD], sk1[HD];            // sort dbuf (u32 keys)
    __shared__ __align__(16) uint2 dec2[HD];      // {bits(v), idx*192}
    __shared__ __align__(16) float4 dpart[8][96]; // decode half-partials
    __shared__ float wred[16];
    __shared__ int   wredi[16];
    __shared__ float wredn[16];
    __shared__ float s_sc[4];
    __shared__ int   s_theta;
    __shared__ u32   s_b1, s_b2, s_b3;
    __shared__ int   wcls[128];                   // per (class, wave) counts
    __shared__ int   sbase[128];                  // exclusive scan
    __shared__ int   cnt8[8];
    __shared__ float loss4[NITER];

    const float* xrow = x + row * DD;
    const float* yrow = y + row * DD;

    for (int i = tid; i < 1152; i += 1024)
        xpad[i] = (i >= DD - 1 && i < 2 * DD - 1) ? xrow[i - (DD - 1)] : 0.f;
    if (tid < DD) yr[tid] = yrow[tid];
    __syncthreads();

    // ---- qn = ||y|| (+ y-count -> global atomic) ----
    if (tid < DD) {
        float p = yr[tid] * yr[tid];
        int   c = (yr[tid] != 0.f) ? 1 : 0;
        for (int o = 32; o; o >>= 1) {
            p += __shfl_xor(p, o, 64);
            c += __shfl_xor(c, o, 64);
        }
        if (lane == 0) { wred[wid] = p; wredi[wid] = c; }
    }
    __syncthreads();
    if (tid == 0) {
        float s = 0.f; int c = 0;
        for (int w = 0; w < 6; ++w) { s += wred[w]; c += wredi[w]; }
        s_sc[0] = sqrtf(s);
        atomicAdd(gcnt, c);
    }
    __syncthreads();
    const float qn = s_sc[0];

    // ---- sim argmax: threads 0..191, 4 consecutive shifts, sliding window ----
    float bv = -INFINITY; int bs = 0x7fffffff; float bn = 0.f;
    if (tid < 192) {
        const float4* xp4 = (const float4*)xpad;
        const float4* yp4 = (const float4*)yr;
        float4 A = xp4[tid];
        const float f0 = A.x * A.x, f1 = A.y * A.y, f2 = A.z * A.z;
        float d0 = 0.f, d1 = 0.f, d2 = 0.f, d3 = 0.f, n0 = 0.f;
#pragma unroll 4
        for (int jc = 0; jc < 96; ++jc) {
            float4 B = xp4[tid + jc + 1];
            float4 Y = yp4[jc];
            d0 += A.x * Y.x; d0 += A.y * Y.y; d0 += A.z * Y.z; d0 += A.w * Y.w;
            d1 += A.y * Y.x; d1 += A.z * Y.y; d1 += A.w * Y.z; d1 += B.x * Y.w;
            d2 += A.z * Y.x; d2 += A.w * Y.y; d2 += B.x * Y.z; d2 += B.y * Y.w;
            d3 += A.w * Y.x; d3 += B.x * Y.y; d3 += B.y * Y.z; d3 += B.z * Y.w;
            n0 += A.x * A.x; n0 += A.y * A.y; n0 += A.z * A.z; n0 += A.w * A.w;
            A = B;
        }
        const float n1 = n0 - f0 + A.x * A.x;
        const float n2 = n1 - f1 + A.y * A.y;
        const float n3 = n2 - f2 + A.z * A.z;
        const int s0 = 4 * tid;
        float sim0 = d0 / (qn * sqrtf(n0) + EPSF);
        float sim1 = d1 / (qn * sqrtf(n1) + EPSF);
        float sim2 = d2 / (qn * sqrtf(n2) + EPSF);
        float sim3 = d3 / (qn * sqrtf(n3) + EPSF);
        bv = sim0; bs = s0; bn = n0;
        if (s0 + 1 < NS && sim1 > bv) { bv = sim1; bs = s0 + 1; bn = n1; }
        if (s0 + 2 < NS && sim2 > bv) { bv = sim2; bs = s0 + 2; bn = n2; }
        if (s0 + 3 < NS && sim3 > bv) { bv = sim3; bs = s0 + 3; bn = n3; }
    }
    for (int o = 32; o; o >>= 1) {
        float v2 = __shfl_xor(bv, o, 64);
        int   i2 = __shfl_xor(bs, o, 64);
        float n2 = __shfl_xor(bn, o, 64);
        if (v2 > bv || (v2 == bv && i2 < bs)) { bv = v2; bs = i2; bn = n2; }
    }
    if (lane == 0) { wred[wid] = bv; wredi[wid] = bs; wredn[wid] = bn; }
    __syncthreads();
    if (tid == 0) {
        float v = wred[0]; int b = wredi[0]; float nn = wredn[0];
        for (int w = 1; w < 16; ++w)
            if (wred[w] > v || (wred[w] == v && wredi[w] < b)) {
                v = wred[w]; b = wredi[w]; nn = wredn[w];
            }
        s_theta = b;
        s_sc[1] = sqrtf(nn) * qn + EPSF;      // dn from carried nrm(theta)
    }
    __syncthreads();
    const int theta = s_theta;
    const float dn = s_sc[1];

    // ---- softmax without max-pass (|z| <= 0.1 by Cauchy-Schwarz) ----
    float xo = 0.f, ez = 0.f;
    if (tid < DD) {
        xo = xpad[theta + tid];
        ez = expf((xo * yr[tid] / dn) / TEMPER_F);
        float p = ez;
        for (int o = 32; o; o >>= 1) p += __shfl_xor(p, o, 64);
        if (lane == 0) wred[wid] = p;
    }
    __syncthreads();
    if (tid == 0) {
        float s = 0.f;
        for (int w = 0; w < 6; ++w) s += wred[w];
        s_sc[3] = s;
    }
    __syncthreads();
    if (tid < DD) xa[tid] = xo * (ez / s_sc[3]);
    __syncthreads();
    if (tid < DD) {
        int sj = tid - (theta - (DD - 1));
        xe_s[tid] = (sj >= 0 && sj < DD) ? xa[sj] : 0.f;
    }
    __syncthreads();
    if (tid < 192) xep[tid] = packh2(xe_s[2 * tid], xe_s[2 * tid + 1]);
    __syncthreads();

    // ---- encoder: K-split 4x, f16 pairs, fdot2 ----
    {
        const int ks = tid >> 8;              // 0..3 (wave-uniform)
        const int c4 = tid & 255;
        const uint4* wq = (const uint4*)wencp + (size_t)(ks * 48) * 256 + c4;
        const u32* xb = xep + ks * 48;
        float4 acc = make_float4(0.f, 0.f, 0.f, 0.f);
#pragma unroll 8
        for (int j2 = 0; j2 < 48; ++j2) {
            u32 xv = xb[j2];                  // broadcast
            uint4 w = wq[(size_t)j2 * 256];
            acc.x = dot2(xv, w.x, acc.x);
            acc.y = dot2(xv, w.y, acc.y);
            acc.z = dot2(xv, w.z, acc.z);
            acc.w = dot2(xv, w.w, acc.w);
        }
        *(float4*)&part[ks][4 * c4] = acc;
    }
    if (tid < 8) cnt8[tid] = 0;
    if (tid < NITER) loss4[tid] = 0.f;
    __syncthreads();

    float oh;
    u32 okey, e;
    {
        oh = part[0][tid] + part[1][tid] + part[2][tid] + part[3][tid] + benc[tid];
        okey = ~flipf(oh);                    // ascending key == descending h
        e = okey;
    }

    // ---- bitonic sort of bare u32 keys (1/thread); dbuf LDS rounds ----
    int par = 0;
    for (int k = 2; k <= HD; k <<= 1) {
        const bool up = (tid & k) == 0;
        for (int j = k >> 1; j > 0; j >>= 1) {
            if (j <= 32) {
                u32 p = __shfl_xor(e, j, 64);
                const bool takeMin = ((tid & j) == 0) == up;
                e = takeMin ? (e < p ? e : p) : (e > p ? e : p);
            } else {                           // j in {64,128,256,512}
                u32* buf = par ? sk1 : sk0; par ^= 1;
                buf[tid] = e;
                __syncthreads();
                u32 p = buf[tid ^ j];
                const bool takeMin = ((tid & j) == 0) == up;
                e = takeMin ? (e < p ? e : p) : (e > p ? e : p);
            }
        }
    }
    if (tid == 255) s_b1 = e;
    if (tid == 511) s_b2 = e;
    if (tid == 767) s_b3 = e;
    __syncthreads();
    const u32 b1 = s_b1, b2 = s_b2, b3 = s_b3;

    // ---- partition: class = 2*quartile + (below-cutoff); ballot compaction ----
    {
        const int myk = (okey <= b1) ? 0 : (okey <= b2) ? 1 : (okey <= b3) ? 2 : 3;
        const int cls = 2 * myk + ((oh > CUTF) ? 0 : 1);
        int myprefix = 0;
        const u64 ltmask = (1ull << lane) - 1;
#pragma unroll
        for (int c = 0; c < 8; ++c) {
            u64 m = __ballot(cls == c);
            if (cls == c) myprefix = __popcll(m & ltmask);
            if (lane == 0) {
                wcls[c * 16 + wid] = (int)__popcll(m);
                atomicAdd(&cnt8[c], (int)__popcll(m));
            }
        }
        __syncthreads();
        if (tid < 128) {
            int v = wcls[tid];
            int inc = v;
            for (int o = 1; o < 64; o <<= 1) {
                int t2 = __shfl_up(inc, o, 64);
                if (lane >= o) inc += t2;
            }
            sbase[tid] = inc - v;             // wave-local exclusive
        }
        __syncthreads();
        if (tid >= 64 && tid < 128) sbase[tid] += sbase[63] + wcls[63];
        __syncthreads();
        const int slot = sbase[cls * 16 + wid] + myprefix;
        dec2[slot] = make_uint2(__float_as_uint(oh), (u32)tid * 192u);
    }
    __syncthreads();

    // ---- decode pass 1: 8 groups of 128 thr = (k, rank-half); 4 cols/thread ----
    {
        const int g8 = tid >> 7;              // 0..7
        const int k  = g8 >> 1;               // wave-uniform
        const int hf = g8 & 1;
        const int gg = tid & 127;
        const bool active = (gg < 96);        // 96 col-quads = 384 cols
        int n = 0;
        if (active) n = (k == 0) ? CD : cnt8[2 * k];
        int r  = hf * 128;
        int r1 = n < r + 128 ? n : r + 128;
        if (r1 < r) r1 = r;
        float4 acc = make_float4(0.f, 0.f, 0.f, 0.f);
        const u32* wd = wdec16 + 2 * gg;      // col-pairs 2gg, 2gg+1
        const int base = k * CD;
        for (; r + 8 <= r1; r += 8) {
#pragma unroll
            for (int q = 0; q < 8; q += 2) {
                uint4 dv = *(const uint4*)&dec2[base + r + q];
                float v0 = __uint_as_float(dv.x);
                uint2 w0 = *(const uint2*)(wd + dv.y);
                float v1 = __uint_as_float(dv.z);
                uint2 w1 = *(const uint2*)(wd + dv.w);
                acc.x += v0 * blo(w0.x); acc.y += v0 * bhi(w0.x);
                acc.z += v0 * blo(w0.y); acc.w += v0 * bhi(w0.y);
                acc.x += v1 * blo(w1.x); acc.y += v1 * bhi(w1.x);
                acc.z += v1 * blo(w1.y); acc.w += v1 * bhi(w1.y);
            }
        }
        for (; r < r1; ++r) {
            uint2 dv = dec2[base + r];
            float v0 = __uint_as_float(dv.x);
            uint2 w0 = *(const uint2*)(wd + dv.y);
            acc.x += v0 * blo(w0.x); acc.y += v0 * bhi(w0.x);
            acc.z += v0 * blo(w0.y); acc.w += v0 * bhi(w0.y);
        }
        if (active) dpart[g8][gg] = acc;
    }
    __syncthreads();

    // ---- decode pass 2: combine halves, store, loss ----
    {
        float l = 0.f;
        if (tid < 512) {
            const int k2 = tid >> 7;          // wave-uniform
            const int q  = tid & 127;
            if (q < 96) {
                float4 a = dpart[2 * k2][q];
                float4 b = dpart[2 * k2 + 1][q];
                float4 bb = *(const float4*)&bdec[4 * q];
                float4 o4;
                o4.x = a.x + b.x + bb.x;
                o4.y = a.y + b.y + bb.y;
                o4.z = a.z + b.z + bb.z;
                o4.w = a.w + b.w + bb.w;
                *(float4*)&out_xdis[((size_t)k2 * NROWS + row) * DD + 4 * q] = o4;
                float4 xv = *(const float4*)&xrow[4 * q];
                float4 yv = *(const float4*)&yr[4 * q];
                float ee;
                ee = o4.x - xv.x; if (yv.x != 0.f) l += ee * ee;
                ee = o4.y - xv.y; if (yv.y != 0.f) l += ee * ee;
                ee = o4.z - xv.z; if (yv.z != 0.f) l += ee * ee;
                ee = o4.w - xv.w; if (yv.w != 0.f) l += ee * ee;
            }
        }
        for (int o = 32; o; o >>= 1) l += __shfl_xor(l, o, 64);
        if (tid < 512 && lane == 0) atomicAdd(&loss4[tid >> 7], l);
    }
    __syncthreads();

    // ---- block loss -> global atomics; last block finalizes ----
    if (tid < NITER) atomicAdd(&gloss[tid], loss4[tid]);
    __threadfence();
    __syncthreads();
    if (tid == 0) {
        int t = __hip_atomic_fetch_add(ticket, 1, __ATOMIC_ACQ_REL,
                                       __HIP_MEMORY_SCOPE_AGENT);
        if (t == NROWS - 1) {
            int total = __hip_atomic_load(gcnt, __ATOMIC_RELAXED,
                                          __HIP_MEMORY_SCOPE_AGENT);
            for (int k = 0; k < NITER; ++k) {
                float s = __hip_atomic_load(&gloss[k], __ATOMIC_RELAXED,
                                            __HIP_MEMORY_SCOPE_AGENT);
                losses[k] = s / (float)total;
            }
        }
    }
}

extern "C" void kernel_launch(void* const* d_in, const int* in_sizes, int n_in,
                              void* d_out, int out_size, void* d_ws, size_t ws_size,
                              hipStream_t stream) {
    const float* x    = (const float*)d_in[0];
    const float* y    = (const float*)d_in[1];
    const float* Wenc = (const float*)d_in[2];
    const float* benc = (const float*)d_in[3];
    const float* Wdec = (const float*)d_in[4];
    const float* bdec = (const float*)d_in[5];

    float* out  = (float*)d_out;
    float* loss = out + (out_size - NITER);

    // workspace: 64B header {gloss[4], gcnt, ticket, pad}, then packed weights
    float* gloss  = (float*)d_ws;
    int*   gcnt   = (int*)d_ws + 4;
    int*   ticket = (int*)d_ws + 5;
    u32*   wencp  = (u32*)d_ws + 16;                       // 196608 u32 (f16 K-pairs)
    u32*   wdec16 = wencp + 192 * HD;                      // 196608 u32 (bf16 col-pairs)

    convert_kernel<<<256, 256, 0, stream>>>(Wenc, Wdec, (u32*)d_ws, wencp,
                                            (uint2*)wdec16);
    fused_kernel<<<NROWS, 1024, 0, stream>>>(x, y, wencp, benc, wdec16, bdec,
                                             out, gloss, gcnt, ticket, loss);
}

// Round 16
// 106.108 us; speedup vs baseline: 1.5893x; 1.5893x over previous
//
#include <hip/hip_runtime.h>
#include <hip/hip_fp16.h>
#include <math.h>

#define DD 384
#define HD 1024
#define CD 256
#define NS 765        // 2*DD-1 shifts
#define NITER 4
#define NROWS 256     // B*T
#define TEMPER_F 10.0f
#define EPSF 1e-6f
#define CUTF 1e-10f

typedef unsigned long long u64;
typedef unsigned int u32;
typedef _Float16 hh2 __attribute__((ext_vector_type(2)));

// monotone float->uint (ascending)
__device__ __forceinline__ u32 flipf(float f) {
    u32 u = __float_as_uint(f);
    return u ^ ((u32)((int)u >> 31) | 0x80000000u);
}
// fp32 -> bf16 (RTNE), packed pair
__device__ __forceinline__ u32 bf16r(float f) {
    u32 u = __float_as_uint(f);
    return (u + 0x7FFFu + ((u >> 16) & 1u)) >> 16;
}
__device__ __forceinline__ u32 pack2bf(float a, float b) {
    return bf16r(a) | (bf16r(b) << 16);
}
__device__ __forceinline__ float blo(u32 p) { return __uint_as_float(p << 16); }
__device__ __forceinline__ float bhi(u32 p) { return __uint_as_float(p & 0xFFFF0000u); }
// fp32 pair -> packed f16 (RTNE)
__device__ __forceinline__ u32 packh2(float a, float b) {
    __half2 p = __floats2half2_rn(a, b);
    return __builtin_bit_cast(u32, p);
}
// fp32 += dot2(f16x2, f16x2)
__device__ __forceinline__ float dot2(u32 a, u32 b, float c) {
#if __has_builtin(__builtin_amdgcn_fdot2)
    return __builtin_amdgcn_fdot2(__builtin_bit_cast(hh2, a),
                                  __builtin_bit_cast(hh2, b), c, false);
#else
    __half2 ah = __builtin_bit_cast(__half2, a);
    __half2 bh = __builtin_bit_cast(__half2, b);
    return fmaf(__half2float(ah.y), __half2float(bh.y),
           fmaf(__half2float(ah.x), __half2float(bh.x), c));
#endif
}

// ---- 0) convert weights: Wenc -> f16 K-paired [192][1024] u32;
//         Wdec -> bf16 col-paired [1024][192] u32 ----
__global__ __launch_bounds__(256) void convert_kernel(
    const float* __restrict__ We, const float* __restrict__ Wd,
    u32* __restrict__ wencp, uint2* __restrict__ wd16)
{
    const int t = blockIdx.x * 256 + threadIdx.x;      // 65536 threads
    for (int i = t; i < 192 * HD; i += 65536) {
        int j2 = i >> 10, c = i & 1023;
        wencp[i] = packh2(We[(2 * j2) * HD + c], We[(2 * j2 + 1) * HD + c]);
    }
    for (int i = t; i < (HD * DD) / 4; i += 65536) {
        float4 v = ((const float4*)Wd)[i];
        wd16[i] = make_uint2(pack2bf(v.x, v.y), pack2bf(v.z, v.w));
    }
}

// One 1024-thread block per row: prep -> fdot2 encoder -> u32-key bitonic sort
// (boundaries only) -> ballot-compaction partition -> 2-pass balanced decode.
// NOTE: loss/ycnt leave the kernel as plain per-row stores; the finalize runs as
// a separate dispatch. In-kernel agent-scope fences/atomics regressed 3x (R6, R15).
__global__ __launch_bounds__(1024) void fused_kernel(
    const float* __restrict__ x, const float* __restrict__ y,
    const u32* __restrict__ wencp, const float* __restrict__ benc,
    const u32* __restrict__ wdec16, const float* __restrict__ bdec,
    float* __restrict__ out_xdis, float* __restrict__ lossp,
    int* __restrict__ ycnt)
{
    const int row  = blockIdx.x;
    const int tid  = threadIdx.x;
    const int lane = tid & 63;
    const int wid  = tid >> 6;       // 0..15

    __shared__ __align__(16) float xpad[1152];
    __shared__ __align__(16) float yr[DD];
    __shared__ float xa[DD];
    __shared__ __align__(16) float xe_s[DD];
    __shared__ u32   xep[192];                    // xe packed f16 pairs
    __shared__ __align__(16) float part[4][HD];   // encoder K-split partials
    __shared__ u32   sk0[HD], sk1[HD];            // sort dbuf (u32 keys)
    __shared__ __align__(16) uint2 dec2[HD];      // {bits(v), idx*192}
    __shared__ __align__(16) float4 dpart[8][96]; // decode half-partials
    __shared__ float wred[16];
    __shared__ int   wredi[16];
    __shared__ float wredn[16];
    __shared__ float s_sc[4];
    __shared__ int   s_theta;
    __shared__ u32   s_b1, s_b2, s_b3;
    __shared__ int   wcls[128];                   // per (class, wave) counts
    __shared__ int   sbase[128];                  // exclusive scan
    __shared__ int   cnt8[8];
    __shared__ float loss4[NITER];

    const float* xrow = x + row * DD;
    const float* yrow = y + row * DD;

    for (int i = tid; i < 1152; i += 1024)
        xpad[i] = (i >= DD - 1 && i < 2 * DD - 1) ? xrow[i - (DD - 1)] : 0.f;
    if (tid < DD) yr[tid] = yrow[tid];
    __syncthreads();

    // ---- qn = ||y|| (+ y-count) ----
    if (tid < DD) {
        float p = yr[tid] * yr[tid];
        int   c = (yr[tid] != 0.f) ? 1 : 0;
        for (int o = 32; o; o >>= 1) {
            p += __shfl_xor(p, o, 64);
            c += __shfl_xor(c, o, 64);
        }
        if (lane == 0) { wred[wid] = p; wredi[wid] = c; }
    }
    __syncthreads();
    if (tid == 0) {
        float s = 0.f; int c = 0;
        for (int w = 0; w < 6; ++w) { s += wred[w]; c += wredi[w]; }
        s_sc[0] = sqrtf(s);
        ycnt[row] = c;
    }
    __syncthreads();
    const float qn = s_sc[0];

    // ---- sim argmax: threads 0..191, 4 consecutive shifts, sliding window ----
    float bv = -INFINITY; int bs = 0x7fffffff; float bn = 0.f;
    if (tid < 192) {
        const float4* xp4 = (const float4*)xpad;
        const float4* yp4 = (const float4*)yr;
        float4 A = xp4[tid];
        const float f0 = A.x * A.x, f1 = A.y * A.y, f2 = A.z * A.z;
        float d0 = 0.f, d1 = 0.f, d2 = 0.f, d3 = 0.f, n0 = 0.f;
#pragma unroll 4
        for (int jc = 0; jc < 96; ++jc) {
            float4 B = xp4[tid + jc + 1];
            float4 Y = yp4[jc];
            d0 += A.x * Y.x; d0 += A.y * Y.y; d0 += A.z * Y.z; d0 += A.w * Y.w;
            d1 += A.y * Y.x; d1 += A.z * Y.y; d1 += A.w * Y.z; d1 += B.x * Y.w;
            d2 += A.z * Y.x; d2 += A.w * Y.y; d2 += B.x * Y.z; d2 += B.y * Y.w;
            d3 += A.w * Y.x; d3 += B.x * Y.y; d3 += B.y * Y.z; d3 += B.z * Y.w;
            n0 += A.x * A.x; n0 += A.y * A.y; n0 += A.z * A.z; n0 += A.w * A.w;
            A = B;
        }
        const float n1 = n0 - f0 + A.x * A.x;
        const float n2 = n1 - f1 + A.y * A.y;
        const float n3 = n2 - f2 + A.z * A.z;
        const int s0 = 4 * tid;
        float sim0 = d0 / (qn * sqrtf(n0) + EPSF);
        float sim1 = d1 / (qn * sqrtf(n1) + EPSF);
        float sim2 = d2 / (qn * sqrtf(n2) + EPSF);
        float sim3 = d3 / (qn * sqrtf(n3) + EPSF);
        bv = sim0; bs = s0; bn = n0;
        if (s0 + 1 < NS && sim1 > bv) { bv = sim1; bs = s0 + 1; bn = n1; }
        if (s0 + 2 < NS && sim2 > bv) { bv = sim2; bs = s0 + 2; bn = n2; }
        if (s0 + 3 < NS && sim3 > bv) { bv = sim3; bs = s0 + 3; bn = n3; }
    }
    for (int o = 32; o; o >>= 1) {
        float v2 = __shfl_xor(bv, o, 64);
        int   i2 = __shfl_xor(bs, o, 64);
        float n2 = __shfl_xor(bn, o, 64);
        if (v2 > bv || (v2 == bv && i2 < bs)) { bv = v2; bs = i2; bn = n2; }
    }
    if (lane == 0) { wred[wid] = bv; wredi[wid] = bs; wredn[wid] = bn; }
    __syncthreads();
    if (tid == 0) {
        float v = wred[0]; int b = wredi[0]; float nn = wredn[0];
        for (int w = 1; w < 16; ++w)
            if (wred[w] > v || (wred[w] == v && wredi[w] < b)) {
                v = wred[w]; b = wredi[w]; nn = wredn[w];
            }
        s_theta = b;
        s_sc[1] = sqrtf(nn) * qn + EPSF;      // dn from carried nrm(theta)
    }
    __syncthreads();
    const int theta = s_theta;
    const float dn = s_sc[1];

    // ---- softmax without max-pass (|z| <= 0.1 by Cauchy-Schwarz) ----
    float xo = 0.f, ez = 0.f;
    if (tid < DD) {
        xo = xpad[theta + tid];
        ez = expf((xo * yr[tid] / dn) / TEMPER_F);
        float p = ez;
        for (int o = 32; o; o >>= 1) p += __shfl_xor(p, o, 64);
        if (lane == 0) wred[wid] = p;
    }
    __syncthreads();
    if (tid == 0) {
        float s = 0.f;
        for (int w = 0; w < 6; ++w) s += wred[w];
        s_sc[3] = s;
    }
    __syncthreads();
    if (tid < DD) xa[tid] = xo * (ez / s_sc[3]);
    __syncthreads();
    if (tid < DD) {
        int sj = tid - (theta - (DD - 1));
        xe_s[tid] = (sj >= 0 && sj < DD) ? xa[sj] : 0.f;
    }
    __syncthreads();
    if (tid < 192) xep[tid] = packh2(xe_s[2 * tid], xe_s[2 * tid + 1]);
    __syncthreads();

    // ---- encoder: K-split 4x, f16 pairs, fdot2 ----
    {
        const int ks = tid >> 8;              // 0..3 (wave-uniform)
        const int c4 = tid & 255;
        const uint4* wq = (const uint4*)wencp + (size_t)(ks * 48) * 256 + c4;
        const u32* xb = xep + ks * 48;
        float4 acc = make_float4(0.f, 0.f, 0.f, 0.f);
#pragma unroll 8
        for (int j2 = 0; j2 < 48; ++j2) {
            u32 xv = xb[j2];                  // broadcast
            uint4 w = wq[(size_t)j2 * 256];
            acc.x = dot2(xv, w.x, acc.x);
            acc.y = dot2(xv, w.y, acc.y);
            acc.z = dot2(xv, w.z, acc.z);
            acc.w = dot2(xv, w.w, acc.w);
        }
        *(float4*)&part[ks][4 * c4] = acc;
    }
    if (tid < 8) cnt8[tid] = 0;
    if (tid < NITER) loss4[tid] = 0.f;
    __syncthreads();

    float oh;
    u32 okey, e;
    {
        oh = part[0][tid] + part[1][tid] + part[2][tid] + part[3][tid] + benc[tid];
        okey = ~flipf(oh);                    // ascending key == descending h
        e = okey;
    }

    // ---- bitonic sort of bare u32 keys (1/thread); dbuf LDS rounds ----
    int par = 0;
    for (int k = 2; k <= HD; k <<= 1) {
        const bool up = (tid & k) == 0;
        for (int j = k >> 1; j > 0; j >>= 1) {
            if (j <= 32) {
                u32 p = __shfl_xor(e, j, 64);
                const bool takeMin = ((tid & j) == 0) == up;
                e = takeMin ? (e < p ? e : p) : (e > p ? e : p);
            } else {                           // j in {64,128,256,512}
                u32* buf = par ? sk1 : sk0; par ^= 1;
                buf[tid] = e;
                __syncthreads();
                u32 p = buf[tid ^ j];
                const bool takeMin = ((tid & j) == 0) == up;
                e = takeMin ? (e < p ? e : p) : (e > p ? e : p);
            }
        }
    }
    if (tid == 255) s_b1 = e;
    if (tid == 511) s_b2 = e;
    if (tid == 767) s_b3 = e;
    __syncthreads();
    const u32 b1 = s_b1, b2 = s_b2, b3 = s_b3;

    // ---- partition: class = 2*quartile + (below-cutoff); ballot compaction ----
    {
        const int myk = (okey <= b1) ? 0 : (okey <= b2) ? 1 : (okey <= b3) ? 2 : 3;
        const int cls = 2 * myk + ((oh > CUTF) ? 0 : 1);
        int myprefix = 0;
        const u64 ltmask = (1ull << lane) - 1;
#pragma unroll
        for (int c = 0; c < 8; ++c) {
            u64 m = __ballot(cls == c);
            if (cls == c) myprefix = __popcll(m & ltmask);
            if (lane == 0) {
                wcls[c * 16 + wid] = (int)__popcll(m);
                atomicAdd(&cnt8[c], (int)__popcll(m));
            }
        }
        __syncthreads();
        if (tid < 128) {
            int v = wcls[tid];
            int inc = v;
            for (int o = 1; o < 64; o <<= 1) {
                int t2 = __shfl_up(inc, o, 64);
                if (lane >= o) inc += t2;
            }
            sbase[tid] = inc - v;             // wave-local exclusive
        }
        __syncthreads();
        if (tid >= 64 && tid < 128) sbase[tid] += sbase[63] + wcls[63];
        __syncthreads();
        const int slot = sbase[cls * 16 + wid] + myprefix;
        dec2[slot] = make_uint2(__float_as_uint(oh), (u32)tid * 192u);
    }
    __syncthreads();

    // ---- decode pass 1: 8 groups of 128 thr = (k, rank-half); 4 cols/thread ----
    {
        const int g8 = tid >> 7;              // 0..7
        const int k  = g8 >> 1;               // wave-uniform
        const int hf = g8 & 1;
        const int gg = tid & 127;
        const bool active = (gg < 96);        // 96 col-quads = 384 cols
        int n = 0;
        if (active) n = (k == 0) ? CD : cnt8[2 * k];
        int r  = hf * 128;
        int r1 = n < r + 128 ? n : r + 128;
        if (r1 < r) r1 = r;
        float4 acc = make_float4(0.f, 0.f, 0.f, 0.f);
        const u32* wd = wdec16 + 2 * gg;      // col-pairs 2gg, 2gg+1
        const int base = k * CD;
        for (; r + 8 <= r1; r += 8) {
#pragma unroll
            for (int q = 0; q < 8; q += 2) {
                uint4 dv = *(const uint4*)&dec2[base + r + q];
                float v0 = __uint_as_float(dv.x);
                uint2 w0 = *(const uint2*)(wd + dv.y);
                float v1 = __uint_as_float(dv.z);
                uint2 w1 = *(const uint2*)(wd + dv.w);
                acc.x += v0 * blo(w0.x); acc.y += v0 * bhi(w0.x);
                acc.z += v0 * blo(w0.y); acc.w += v0 * bhi(w0.y);
                acc.x += v1 * blo(w1.x); acc.y += v1 * bhi(w1.x);
                acc.z += v1 * blo(w1.y); acc.w += v1 * bhi(w1.y);
            }
        }
        for (; r < r1; ++r) {
            uint2 dv = dec2[base + r];
            float v0 = __uint_as_float(dv.x);
            uint2 w0 = *(const uint2*)(wd + dv.y);
            acc.x += v0 * blo(w0.x); acc.y += v0 * bhi(w0.x);
            acc.z += v0 * blo(w0.y); acc.w += v0 * bhi(w0.y);
        }
        if (active) dpart[g8][gg] = acc;
    }
    __syncthreads();

    // ---- decode pass 2: combine halves, store, loss ----
    {
        float l = 0.f;
        if (tid < 512) {
            const int k2 = tid >> 7;          // wave-uniform
            const int q  = tid & 127;
            if (q < 96) {
                float4 a = dpart[2 * k2][q];
                float4 b = dpart[2 * k2 + 1][q];
                float4 bb = *(const float4*)&bdec[4 * q];
                float4 o4;
                o4.x = a.x + b.x + bb.x;
                o4.y = a.y + b.y + bb.y;
                o4.z = a.z + b.z + bb.z;
                o4.w = a.w + b.w + bb.w;
                *(float4*)&out_xdis[((size_t)k2 * NROWS + row) * DD + 4 * q] = o4;
                float4 xv = *(const float4*)&xrow[4 * q];
                float4 yv = *(const float4*)&yr[4 * q];
                float ee;
                ee = o4.x - xv.x; if (yv.x != 0.f) l += ee * ee;
                ee = o4.y - xv.y; if (yv.y != 0.f) l += ee * ee;
                ee = o4.z - xv.z; if (yv.z != 0.f) l += ee * ee;
                ee = o4.w - xv.w; if (yv.w != 0.f) l += ee * ee;
            }
        }
        for (int o = 32; o; o >>= 1) l += __shfl_xor(l, o, 64);
        if (tid < 512 && lane == 0) atomicAdd(&loss4[tid >> 7], l);
    }
    __syncthreads();
    if (tid < NITER) lossp[row * NITER + tid] = loss4[tid];
}

// ---- finalize: losses[k] = sum_rows lossp / sum_rows ycnt ----
__global__ __launch_bounds__(256) void finalize2(
    const float* __restrict__ lossp, const int* __restrict__ ycnt,
    float* __restrict__ losses)
{
    const int tid = threadIdx.x, lane = tid & 63, w = tid >> 6;
    __shared__ int ctot[4];
    int c = ycnt[tid];
    for (int o = 32; o; o >>= 1) c += __shfl_xor(c, o, 64);
    if (lane == 0) ctot[w] = c;
    __syncthreads();
    const int total = ctot[0] + ctot[1] + ctot[2] + ctot[3];
    float s = lossp[lane * NITER + w] + lossp[(lane + 64) * NITER + w]
            + lossp[(lane + 128) * NITER + w] + lossp[(lane + 192) * NITER + w];
    for (int o = 32; o; o >>= 1) s += __shfl_xor(s, o, 64);
    if (lane == 0) losses[w] = s / (float)total;
}

extern "C" void kernel_launch(void* const* d_in, const int* in_sizes, int n_in,
                              void* d_out, int out_size, void* d_ws, size_t ws_size,
                              hipStream_t stream) {
    const float* x    = (const float*)d_in[0];
    const float* y    = (const float*)d_in[1];
    const float* Wenc = (const float*)d_in[2];
    const float* benc = (const float*)d_in[3];
    const float* Wdec = (const float*)d_in[4];
    const float* bdec = (const float*)d_in[5];

    float* out  = (float*)d_out;
    float* loss = out + (out_size - NITER);

    // workspace (all regions fully written before read each launch; 16B-aligned)
    float* lossp  = (float*)d_ws;                          // 1024 floats
    int*   ycnt   = (int*)(lossp + NROWS * NITER);         // 256 ints
    u32*   wencp  = (u32*)(ycnt + NROWS);                  // 196608 u32 (f16 K-pairs)
    u32*   wdec16 = wencp + 192 * HD;                      // 196608 u32 (bf16 col-pairs)

    convert_kernel<<<256, 256, 0, stream>>>(Wenc, Wdec, wencp, (uint2*)wdec16);
    fused_kernel<<<NROWS, 1024, 0, stream>>>(x, y, wencp, benc, wdec16, bdec,
                                             out, lossp, ycnt);
    finalize2<<<1, 256, 0, stream>>>(lossp, ycnt, loss);
}

// Round 17
// 102.816 us; speedup vs baseline: 1.6402x; 1.0320x over previous
//
#include <hip/hip_runtime.h>
#include <hip/hip_fp16.h>
#include <math.h>

#define DD 384
#define HD 1024
#define CD 256
#define NS 765        // 2*DD-1 shifts
#define NITER 4
#define NROWS 256     // B*T
#define TEMPER_F 10.0f
#define EPSF 1e-6f
#define CUTF 1e-10f

typedef unsigned long long u64;
typedef unsigned int u32;
typedef _Float16 hh2 __attribute__((ext_vector_type(2)));

// monotone float->uint (ascending)
__device__ __forceinline__ u32 flipf(float f) {
    u32 u = __float_as_uint(f);
    return u ^ ((u32)((int)u >> 31) | 0x80000000u);
}
// fp32 -> bf16 (RTNE), packed pair
__device__ __forceinline__ u32 bf16r(float f) {
    u32 u = __float_as_uint(f);
    return (u + 0x7FFFu + ((u >> 16) & 1u)) >> 16;
}
__device__ __forceinline__ u32 pack2bf(float a, float b) {
    return bf16r(a) | (bf16r(b) << 16);
}
__device__ __forceinline__ float blo(u32 p) { return __uint_as_float(p << 16); }
__device__ __forceinline__ float bhi(u32 p) { return __uint_as_float(p & 0xFFFF0000u); }
// fp32 pair -> packed f16 (RTNE)
__device__ __forceinline__ u32 packh2(float a, float b) {
    __half2 p = __floats2half2_rn(a, b);
    return __builtin_bit_cast(u32, p);
}
// fp32 += dot2(f16x2, f16x2)
__device__ __forceinline__ float dot2(u32 a, u32 b, float c) {
#if __has_builtin(__builtin_amdgcn_fdot2)
    return __builtin_amdgcn_fdot2(__builtin_bit_cast(hh2, a),
                                  __builtin_bit_cast(hh2, b), c, false);
#else
    __half2 ah = __builtin_bit_cast(__half2, a);
    __half2 bh = __builtin_bit_cast(__half2, b);
    return fmaf(__half2float(ah.y), __half2float(bh.y),
           fmaf(__half2float(ah.x), __half2float(bh.x), c));
#endif
}

// ---- 0) convert weights: Wenc -> f16 K-paired [192][1024] u32;
//         Wdec -> bf16 col-paired [1024][192] u32 ----
__global__ __launch_bounds__(256) void convert_kernel(
    const float* __restrict__ We, const float* __restrict__ Wd,
    u32* __restrict__ wencp, uint2* __restrict__ wd16)
{
    const int t = blockIdx.x * 256 + threadIdx.x;      // 65536 threads
    for (int i = t; i < 192 * HD; i += 65536) {
        int j2 = i >> 10, c = i & 1023;
        wencp[i] = packh2(We[(2 * j2) * HD + c], We[(2 * j2 + 1) * HD + c]);
    }
    for (int i = t; i < (HD * DD) / 4; i += 65536) {
        float4 v = ((const float4*)Wd)[i];
        wd16[i] = make_uint2(pack2bf(v.x, v.y), pack2bf(v.z, v.w));
    }
}

// One 1024-thread block per row: prep -> fdot2 encoder -> HISTOGRAM SELECT
// (exact rank-255/511/767 boundary keys; replaces full bitonic sort) ->
// ballot-compaction partition -> 2-pass balanced decode.
// NOTE: loss/ycnt leave the kernel as plain per-row stores; finalize is a
// separate dispatch. Agent-scope fences/atomics in-kernel regressed 3x (R6,R15).
__global__ __launch_bounds__(1024) void fused_kernel(
    const float* __restrict__ x, const float* __restrict__ y,
    const u32* __restrict__ wencp, const float* __restrict__ benc,
    const u32* __restrict__ wdec16, const float* __restrict__ bdec,
    float* __restrict__ out_xdis, float* __restrict__ lossp,
    int* __restrict__ ycnt)
{
    const int row  = blockIdx.x;
    const int tid  = threadIdx.x;
    const int lane = tid & 63;
    const int wid  = tid >> 6;       // 0..15

    __shared__ __align__(16) float xpad[1152];
    __shared__ __align__(16) float yr[DD];
    __shared__ float xa[DD];
    __shared__ __align__(16) float xe_s[DD];
    __shared__ u32   xep[192];                    // xe packed f16 pairs
    __shared__ __align__(16) float part[4][HD];   // enc partials; reused as hist[4096]
    __shared__ __align__(16) uint2 dec2[HD];      // {bits(v), idx*192}
    __shared__ __align__(16) float4 dpart[8][96]; // decode half-partials
    __shared__ float wred[16];
    __shared__ int   wredi[16];
    __shared__ float wredn[16];
    __shared__ int   wbase16[16];
    __shared__ float s_sc[4];
    __shared__ int   s_theta;
    __shared__ u32   s_b[3];
    __shared__ int   sbinB[3], srankB[3], s_cc[3];
    __shared__ u32   cand[3][64];
    __shared__ int   wcls[128];                   // per (class, wave) counts
    __shared__ int   sbase[128];                  // exclusive scan
    __shared__ int   cnt8[8];
    __shared__ float loss4[NITER];

    const float* xrow = x + row * DD;
    const float* yrow = y + row * DD;

    for (int i = tid; i < 1152; i += 1024)
        xpad[i] = (i >= DD - 1 && i < 2 * DD - 1) ? xrow[i - (DD - 1)] : 0.f;
    if (tid < DD) yr[tid] = yrow[tid];
    __syncthreads();

    // ---- qn = ||y|| (+ y-count) ----
    if (tid < DD) {
        float p = yr[tid] * yr[tid];
        int   c = (yr[tid] != 0.f) ? 1 : 0;
        for (int o = 32; o; o >>= 1) {
            p += __shfl_xor(p, o, 64);
            c += __shfl_xor(c, o, 64);
        }
        if (lane == 0) { wred[wid] = p; wredi[wid] = c; }
    }
    __syncthreads();
    if (tid == 0) {
        float s = 0.f; int c = 0;
        for (int w = 0; w < 6; ++w) { s += wred[w]; c += wredi[w]; }
        s_sc[0] = sqrtf(s);
        ycnt[row] = c;
    }
    __syncthreads();
    const float qn = s_sc[0];

    // ---- sim argmax: threads 0..191, 4 consecutive shifts, sliding window ----
    float bv = -INFINITY; int bs = 0x7fffffff; float bn = 0.f;
    if (tid < 192) {
        const float4* xp4 = (const float4*)xpad;
        const float4* yp4 = (const float4*)yr;
        float4 A = xp4[tid];
        const float f0 = A.x * A.x, f1 = A.y * A.y, f2 = A.z * A.z;
        float d0 = 0.f, d1 = 0.f, d2 = 0.f, d3 = 0.f, n0 = 0.f;
#pragma unroll 4
        for (int jc = 0; jc < 96; ++jc) {
            float4 B = xp4[tid + jc + 1];
            float4 Y = yp4[jc];
            d0 += A.x * Y.x; d0 += A.y * Y.y; d0 += A.z * Y.z; d0 += A.w * Y.w;
            d1 += A.y * Y.x; d1 += A.z * Y.y; d1 += A.w * Y.z; d1 += B.x * Y.w;
            d2 += A.z * Y.x; d2 += A.w * Y.y; d2 += B.x * Y.z; d2 += B.y * Y.w;
            d3 += A.w * Y.x; d3 += B.x * Y.y; d3 += B.y * Y.z; d3 += B.z * Y.w;
            n0 += A.x * A.x; n0 += A.y * A.y; n0 += A.z * A.z; n0 += A.w * A.w;
            A = B;
        }
        const float n1 = n0 - f0 + A.x * A.x;
        const float n2 = n1 - f1 + A.y * A.y;
        const float n3 = n2 - f2 + A.z * A.z;
        const int s0 = 4 * tid;
        float sim0 = d0 / (qn * sqrtf(n0) + EPSF);
        float sim1 = d1 / (qn * sqrtf(n1) + EPSF);
        float sim2 = d2 / (qn * sqrtf(n2) + EPSF);
        float sim3 = d3 / (qn * sqrtf(n3) + EPSF);
        bv = sim0; bs = s0; bn = n0;
        if (s0 + 1 < NS && sim1 > bv) { bv = sim1; bs = s0 + 1; bn = n1; }
        if (s0 + 2 < NS && sim2 > bv) { bv = sim2; bs = s0 + 2; bn = n2; }
        if (s0 + 3 < NS && sim3 > bv) { bv = sim3; bs = s0 + 3; bn = n3; }
    }
    for (int o = 32; o; o >>= 1) {
        float v2 = __shfl_xor(bv, o, 64);
        int   i2 = __shfl_xor(bs, o, 64);
        float n2 = __shfl_xor(bn, o, 64);
        if (v2 > bv || (v2 == bv && i2 < bs)) { bv = v2; bs = i2; bn = n2; }
    }
    if (lane == 0) { wred[wid] = bv; wredi[wid] = bs; wredn[wid] = bn; }
    __syncthreads();
    if (tid == 0) {
        float v = wred[0]; int b = wredi[0]; float nn = wredn[0];
        for (int w = 1; w < 16; ++w)
            if (wred[w] > v || (wred[w] == v && wredi[w] < b)) {
                v = wred[w]; b = wredi[w]; nn = wredn[w];
            }
        s_theta = b;
        s_sc[1] = sqrtf(nn) * qn + EPSF;      // dn from carried nrm(theta)
    }
    __syncthreads();
    const int theta = s_theta;
    const float dn = s_sc[1];

    // ---- softmax without max-pass (|z| <= 0.1 by Cauchy-Schwarz) ----
    float xo = 0.f, ez = 0.f;
    if (tid < DD) {
        xo = xpad[theta + tid];
        ez = expf((xo * yr[tid] / dn) / TEMPER_F);
        float p = ez;
        for (int o = 32; o; o >>= 1) p += __shfl_xor(p, o, 64);
        if (lane == 0) wred[wid] = p;
    }
    __syncthreads();
    if (tid == 0) {
        float s = 0.f;
        for (int w = 0; w < 6; ++w) s += wred[w];
        s_sc[3] = s;
    }
    __syncthreads();
    if (tid < DD) xa[tid] = xo * (ez / s_sc[3]);
    __syncthreads();
    if (tid < DD) {
        int sj = tid - (theta - (DD - 1));
        xe_s[tid] = (sj >= 0 && sj < DD) ? xa[sj] : 0.f;
    }
    __syncthreads();
    if (tid < 192) xep[tid] = packh2(xe_s[2 * tid], xe_s[2 * tid + 1]);
    __syncthreads();

    // ---- encoder: K-split 4x, f16 pairs, fdot2 ----
    {
        const int ks = tid >> 8;              // 0..3 (wave-uniform)
        const int c4 = tid & 255;
        const uint4* wq = (const uint4*)wencp + (size_t)(ks * 48) * 256 + c4;
        const u32* xb = xep + ks * 48;
        float4 acc = make_float4(0.f, 0.f, 0.f, 0.f);
#pragma unroll 8
        for (int j2 = 0; j2 < 48; ++j2) {
            u32 xv = xb[j2];                  // broadcast
            uint4 w = wq[(size_t)j2 * 256];
            acc.x = dot2(xv, w.x, acc.x);
            acc.y = dot2(xv, w.y, acc.y);
            acc.z = dot2(xv, w.z, acc.z);
            acc.w = dot2(xv, w.w, acc.w);
        }
        *(float4*)&part[ks][4 * c4] = acc;
    }
    if (tid < 8) cnt8[tid] = 0;
    if (tid < NITER) loss4[tid] = 0.f;
    __syncthreads();

    const float oh = part[0][tid] + part[1][tid] + part[2][tid] + part[3][tid]
                   + benc[tid];
    const u32 okey = ~flipf(oh);              // ascending key == descending h
    __syncthreads();                          // all reads of part done

    // ---- histogram select: exact boundary keys at ranks 255/511/767 ----
    u32* hist = (u32*)part;                   // 4096 bins aliased on dead partials
    {
        hist[tid] = 0; hist[tid + 1024] = 0;
        hist[tid + 2048] = 0; hist[tid + 3072] = 0;
        if (tid < 192) cand[tid >> 6][tid & 63] = 0xFFFFFFFFu;
        if (tid < 3) s_cc[tid] = 0;
        __syncthreads();
        atomicAdd(&hist[okey >> 20], 1u);
        __syncthreads();
        // hierarchical exclusive scan: 4 bins/thread
        const int t4 = tid << 2;
        const u32 l0 = hist[t4], l1 = hist[t4 + 1], l2 = hist[t4 + 2], l3 = hist[t4 + 3];
        const int s = (int)(l0 + l1 + l2 + l3);
        int inc = s;
        for (int o = 1; o < 64; o <<= 1) {
            int u = __shfl_up(inc, o, 64);
            if (lane >= o) inc += u;
        }
        if (lane == 63) wredi[wid] = inc;
        __syncthreads();
        if (tid == 0) {
            int acc = 0;
            for (int w = 0; w < 16; ++w) { wbase16[w] = acc; acc += wredi[w]; }
        }
        __syncthreads();
        const int c0 = wbase16[wid] + inc - s;            // cum before bin t4
        const int c1 = c0 + (int)l0, c2 = c1 + (int)l1, c3 = c2 + (int)l2;
        const int c4e = c3 + (int)l3;
#pragma unroll
        for (int i = 0; i < 3; ++i) {
            const int R = 255 + (i << 8);
            if (R >= c0 && R < c1)      { sbinB[i] = t4;     srankB[i] = R - c0; }
            else if (R >= c1 && R < c2) { sbinB[i] = t4 + 1; srankB[i] = R - c1; }
            else if (R >= c2 && R < c3) { sbinB[i] = t4 + 2; srankB[i] = R - c2; }
            else if (R >= c3 && R < c4e){ sbinB[i] = t4 + 3; srankB[i] = R - c3; }
        }
        __syncthreads();
        // extract candidates of the 3 boundary bins
        const int myb = (int)(okey >> 20);
#pragma unroll
        for (int i = 0; i < 3; ++i) {
            if (myb == sbinB[i]) {
                int slot = atomicAdd(&s_cc[i], 1);
                if (slot < 64) cand[i][slot] = okey;
            }
        }
        __syncthreads();
        // 3 waves each sort 64 candidates in-register; pick intra-bin rank
        if (wid < 3) {
            u32 v = cand[wid][lane];
            for (int k2 = 2; k2 <= 64; k2 <<= 1) {
                for (int j = k2 >> 1; j > 0; j >>= 1) {
                    u32 p = __shfl_xor(v, j, 64);
                    const bool takeMin = ((lane & j) == 0) == ((lane & k2) == 0);
                    v = takeMin ? (v < p ? v : p) : (v > p ? v : p);
                }
            }
            if (lane == srankB[wid]) s_b[wid] = v;
        }
        __syncthreads();
    }
    const u32 b1 = s_b[0], b2 = s_b[1], b3 = s_b[2];

    // ---- partition: class = 2*quartile + (below-cutoff); ballot compaction ----
    {
        const int myk = (okey <= b1) ? 0 : (okey <= b2) ? 1 : (okey <= b3) ? 2 : 3;
        const int cls = 2 * myk + ((oh > CUTF) ? 0 : 1);
        int myprefix = 0;
        const u64 ltmask = (1ull << lane) - 1;
#pragma unroll
        for (int c = 0; c < 8; ++c) {
            u64 m = __ballot(cls == c);
            if (cls == c) myprefix = __popcll(m & ltmask);
            if (lane == 0) {
                wcls[c * 16 + wid] = (int)__popcll(m);
                atomicAdd(&cnt8[c], (int)__popcll(m));
            }
        }
        __syncthreads();
        if (tid < 128) {
            int v = wcls[tid];
            int inc = v;
            for (int o = 1; o < 64; o <<= 1) {
                int t2 = __shfl_up(inc, o, 64);
                if (lane >= o) inc += t2;
            }
            sbase[tid] = inc - v;             // wave-local exclusive
        }
        __syncthreads();
        if (tid >= 64 && tid < 128) sbase[tid] += sbase[63] + wcls[63];
        __syncthreads();
        const int slot = sbase[cls * 16 + wid] + myprefix;
        dec2[slot] = make_uint2(__float_as_uint(oh), (u32)tid * 192u);
    }
    __syncthreads();

    // ---- decode pass 1: 8 groups of 128 thr = (k, rank-half); 4 cols/thread ----
    {
        const int g8 = tid >> 7;              // 0..7
        const int k  = g8 >> 1;               // wave-uniform
        const int hf = g8 & 1;
        const int gg = tid & 127;
        const bool active = (gg < 96);        // 96 col-quads = 384 cols
        int n = 0;
        if (active) n = (k == 0) ? CD : cnt8[2 * k];
        int r  = hf * 128;
        int r1 = n < r + 128 ? n : r + 128;
        if (r1 < r) r1 = r;
        float4 acc = make_float4(0.f, 0.f, 0.f, 0.f);
        const u32* wd = wdec16 + 2 * gg;      // col-pairs 2gg, 2gg+1
        const int base = k * CD;
        for (; r + 8 <= r1; r += 8) {
#pragma unroll
            for (int q = 0; q < 8; q += 2) {
                uint4 dv = *(const uint4*)&dec2[base + r + q];
                float v0 = __uint_as_float(dv.x);
                uint2 w0 = *(const uint2*)(wd + dv.y);
                float v1 = __uint_as_float(dv.z);
                uint2 w1 = *(const uint2*)(wd + dv.w);
                acc.x += v0 * blo(w0.x); acc.y += v0 * bhi(w0.x);
                acc.z += v0 * blo(w0.y); acc.w += v0 * bhi(w0.y);
                acc.x += v1 * blo(w1.x); acc.y += v1 * bhi(w1.x);
                acc.z += v1 * blo(w1.y); acc.w += v1 * bhi(w1.y);
            }
        }
        for (; r < r1; ++r) {
            uint2 dv = dec2[base + r];
            float v0 = __uint_as_float(dv.x);
            uint2 w0 = *(const uint2*)(wd + dv.y);
            acc.x += v0 * blo(w0.x); acc.y += v0 * bhi(w0.x);
            acc.z += v0 * blo(w0.y); acc.w += v0 * bhi(w0.y);
        }
        if (active) dpart[g8][gg] = acc;
    }
    __syncthreads();

    // ---- decode pass 2: combine halves, store, loss ----
    {
        float l = 0.f;
        if (tid < 512) {
            const int k2 = tid >> 7;          // wave-uniform
            const int q  = tid & 127;
            if (q < 96) {
                float4 a = dpart[2 * k2][q];
                float4 b = dpart[2 * k2 + 1][q];
                float4 bb = *(const float4*)&bdec[4 * q];
                float4 o4;
                o4.x = a.x + b.x + bb.x;
                o4.y = a.y + b.y + bb.y;
                o4.z = a.z + b.z + bb.z;
                o4.w = a.w + b.w + bb.w;
                *(float4*)&out_xdis[((size_t)k2 * NROWS + row) * DD + 4 * q] = o4;
                float4 xv = *(const float4*)&xrow[4 * q];
                float4 yv = *(const float4*)&yr[4 * q];
                float ee;
                ee = o4.x - xv.x; if (yv.x != 0.f) l += ee * ee;
                ee = o4.y - xv.y; if (yv.y != 0.f) l += ee * ee;
                ee = o4.z - xv.z; if (yv.z != 0.f) l += ee * ee;
                ee = o4.w - xv.w; if (yv.w != 0.f) l += ee * ee;
            }
        }
        for (int o = 32; o; o >>= 1) l += __shfl_xor(l, o, 64);
        if (tid < 512 && lane == 0) atomicAdd(&loss4[tid >> 7], l);
    }
    __syncthreads();
    if (tid < NITER) lossp[row * NITER + tid] = loss4[tid];
}

// ---- finalize: losses[k] = sum_rows lossp / sum_rows ycnt ----
__global__ __launch_bounds__(256) void finalize2(
    const float* __restrict__ lossp, const int* __restrict__ ycnt,
    float* __restrict__ losses)
{
    const int tid = threadIdx.x, lane = tid & 63, w = tid >> 6;
    __shared__ int ctot[4];
    int c = ycnt[tid];
    for (int o = 32; o; o >>= 1) c += __shfl_xor(c, o, 64);
    if (lane == 0) ctot[w] = c;
    __syncthreads();
    const int total = ctot[0] + ctot[1] + ctot[2] + ctot[3];
    float s = lossp[lane * NITER + w] + lossp[(lane + 64) * NITER + w]
            + lossp[(lane + 128) * NITER + w] + lossp[(lane + 192) * NITER + w];
    for (int o = 32; o; o >>= 1) s += __shfl_xor(s, o, 64);
    if (lane == 0) losses[w] = s / (float)total;
}

extern "C" void kernel_launch(void* const* d_in, const int* in_sizes, int n_in,
                              void* d_out, int out_size, void* d_ws, size_t ws_size,
                              hipStream_t stream) {
    const float* x    = (const float*)d_in[0];
    const float* y    = (const float*)d_in[1];
    const float* Wenc = (const float*)d_in[2];
    const float* benc = (const float*)d_in[3];
    const float* Wdec = (const float*)d_in[4];
    const float* bdec = (const float*)d_in[5];

    float* out  = (float*)d_out;
    float* loss = out + (out_size - NITER);

    // workspace (all regions fully written before read each launch; 16B-aligned)
    float* lossp  = (float*)d_ws;                          // 1024 floats
    int*   ycnt   = (int*)(lossp + NROWS * NITER);         // 256 ints
    u32*   wencp  = (u32*)(ycnt + NROWS);                  // 196608 u32 (f16 K-pairs)
    u32*   wdec16 = wencp + 192 * HD;                      // 196608 u32 (bf16 col-pairs)

    convert_kernel<<<256, 256, 0, stream>>>(Wenc, Wdec, wencp, (uint2*)wdec16);
    fused_kernel<<<NROWS, 1024, 0, stream>>>(x, y, wencp, benc, wdec16, bdec,
                                             out, lossp, ycnt);
    finalize2<<<1, 256, 0, stream>>>(lossp, ycnt, loss);
}